// Round 1
// 1117.385 us; speedup vs baseline: 1.0323x; 1.0323x over previous
//
#include <hip/hip_runtime.h>
#include <hip/hip_fp16.h>
#include <math.h>
#include <stdint.h>

#define B_ 256
#define C_ 3
#define IMG_ 32
#define D_ 256
#define H_ 8
#define HD_ 32
#define T1_ 65
#define MLP_H_ 2048
#define HEAD_H_ 8192
#define NCLS 10
#define PDIM 48
#define M_ROWS (B_*T1_)   // 16640

typedef _Float16 f16;
typedef _Float16 f16x8 __attribute__((ext_vector_type(8)));
typedef _Float16 f16x4 __attribute__((ext_vector_type(4)));
typedef _Float16 f16x2 __attribute__((ext_vector_type(2)));
typedef float f32x4 __attribute__((ext_vector_type(4)));

typedef const void __attribute__((address_space(1))) glob_cv;
typedef void __attribute__((address_space(3))) lds_v;

__device__ __forceinline__ void async16(const void* g, void* l) {
    __builtin_amdgcn_global_load_lds((glob_cv*)g, (lds_v*)l, 16, 0, 0);
}

// ---------------- fused weight prep: 6 transposes + WpT build, one launch ----
// transpose tiles: [0,384) qkv (24x8 x2), [384,1408) mlp1 (64x8 x2),
// [1408,2432) mlp2 (8x64 x2), [2432,2496) wpT build
__global__ __launch_bounds__(256) void prep_weights(
        const float* __restrict__ qkv_w, const float* __restrict__ mlp1_w,
        const float* __restrict__ mlp2_w, const float* __restrict__ Wp,
        f16* __restrict__ w_qkv_t, f16* __restrict__ w_mlp1_t,
        f16* __restrict__ w_mlp2_t, f16* __restrict__ wpT) {
    int id = blockIdx.x;
    if (id >= 2432) {   // WpT: Wp f32 [48][256] -> f16 [256][64] (j-pad 0)
        int idx = (id - 2432) * 256 + threadIdx.x;
        int d = idx >> 6, j = idx & 63;
        wpT[idx] = (j < PDIM) ? (f16)Wp[j * D_ + d] : (f16)0.f;
        return;
    }
    const float* W; f16* Wt; int K, N, nbx, rel;
    if (id < 384) {
        int L = id >= 192; rel = id - L * 192;
        W = qkv_w + (size_t)L * D_ * 768; Wt = w_qkv_t + (size_t)L * 768 * 256;
        K = 256; N = 768; nbx = 24;
    } else if (id < 1408) {
        int L = (id - 384) >= 512; rel = (id - 384) - L * 512;
        W = mlp1_w + (size_t)L * D_ * 2048; Wt = w_mlp1_t + (size_t)L * 2048 * 256;
        K = 256; N = 2048; nbx = 64;
    } else {
        int L = (id - 1408) >= 512; rel = (id - 1408) - L * 512;
        W = mlp2_w + (size_t)L * 2048 * 256; Wt = w_mlp2_t + (size_t)L * 256 * 2048;
        K = 2048; N = 256; nbx = 8;
    }
    int bx = rel % nbx, by = rel / nbx;
    int n0 = bx * 32, k0 = by * 32;
    __shared__ float L2d[32][33];
    int t = threadIdx.x;
    int r = t >> 3, c4 = (t & 7) * 4;
    const float4 v = *(const float4*)(W + (size_t)(k0 + r) * N + n0 + c4);
    L2d[r][c4] = v.x; L2d[r][c4 + 1] = v.y; L2d[r][c4 + 2] = v.z; L2d[r][c4 + 3] = v.w;
    __syncthreads();
    f16x4 h;
    h[0] = (f16)L2d[c4][r]; h[1] = (f16)L2d[c4 + 1][r];
    h[2] = (f16)L2d[c4 + 2][r]; h[3] = (f16)L2d[c4 + 3][r];
    *(f16x4*)(Wt + (size_t)(n0 + r) * K + k0 + c4) = h;
}

// ---------------- patch embed via MFMA + cls + positional encoding ------------
__global__ __launch_bounds__(256) void patch_mfma(
        const float* __restrict__ x, const float* __restrict__ cls,
        const f16* __restrict__ WpT, const float* __restrict__ bp,
        float* __restrict__ out) {
    int b = blockIdx.x;
    __shared__ float xs[3072];
    __shared__ __align__(16) f16 Ap[64 * 64];
    __shared__ __align__(16) f16 Bp[256 * 64];
    int tid = threadIdx.x;
    int lane = tid & 63, wid = tid >> 6;
    int lr = lane & 15, kq = lane >> 4;

    for (int i = tid; i < 768; i += 256)
        ((float4*)xs)[i] = ((const float4*)(x + (size_t)b * 3072))[i];
    for (int i = tid; i < 2048; i += 256)
        async16(WpT + (size_t)i * 8, &Bp[i * 8]);
    __syncthreads();
    for (int i = tid; i < 64 * 64; i += 256) {
        int t = i >> 6, j = i & 63;
        float val = 0.f;
        if (j < PDIM) {
            int py = t >> 3, px = t & 7;
            int c = j >> 4, rr = j & 15;
            int iy = rr >> 2, ix = rr & 3;
            val = xs[c * 1024 + (py * 4 + iy) * 32 + px * 4 + ix];
        }
        Ap[i] = (f16)val;
    }
    __syncthreads();

    for (int tile = wid; tile < 64; tile += 4) {
        int mi = tile >> 4, ni = tile & 15;
        f32x4 acc = {0.f, 0.f, 0.f, 0.f};
        #pragma unroll
        for (int ks = 0; ks < 2; ++ks) {
            f16x8 a = *(const f16x8*)&Ap[(mi * 16 + lr) * 64 + ks * 32 + kq * 8];
            f16x8 bb = *(const f16x8*)&Bp[(ni * 16 + lr) * 64 + ks * 32 + kq * 8];
            acc = __builtin_amdgcn_mfma_f32_16x16x32_f16(a, bb, acc, 0, 0, 0);
        }
        int d = ni * 16 + lr;
        float div = __expf((float)(d & ~1) * (-9.210340371976184f / 256.0f));
        #pragma unroll
        for (int r = 0; r < 4; ++r) {
            int t = 1 + mi * 16 + kq * 4 + r;
            float ang = (float)t * div;
            float pe = (d & 1) ? __cosf(ang) : __sinf(ang);
            out[((size_t)b * T1_ + t) * D_ + d] = acc[r] + bp[d] + pe;
        }
    }
    // row 0: cls + pe(0,d);  pe(0,even)=sin0=0, pe(0,odd)=cos0=1
    out[(size_t)b * T1_ * D_ + tid] = cls[tid] + ((tid & 1) ? 1.f : 0.f);
}

// ---------------- LayerNorm over (T1,D) per batch, 1024 thr, write fp16 ------
__global__ __launch_bounds__(1024) void ln_kernel(
        const float* __restrict__ xin, const float* __restrict__ w,
        const float* __restrict__ bb, f16* __restrict__ hout) {
    int b = blockIdx.x;
    const float4* x4 = (const float4*)(xin + (size_t)b * (T1_ * D_));
    const float4* w4 = (const float4*)w;
    const float4* b4 = (const float4*)bb;
    int tid = threadIdx.x;
    float s = 0.f, s2 = 0.f;
    for (int i = tid; i < 4160; i += 1024) {
        float4 v = x4[i];
        s  += v.x + v.y + v.z + v.w;
        s2 += v.x * v.x + v.y * v.y + v.z * v.z + v.w * v.w;
    }
    #pragma unroll
    for (int o = 32; o > 0; o >>= 1) { s += __shfl_down(s, o); s2 += __shfl_down(s2, o); }
    __shared__ float rs[16], rs2[16];
    __shared__ float mu_s, rstd_s;
    int wid = tid >> 6;
    if ((tid & 63) == 0) { rs[wid] = s; rs2[wid] = s2; }
    __syncthreads();
    if (tid == 0) {
        float S = 0.f, S2 = 0.f;
        #pragma unroll
        for (int i = 0; i < 16; ++i) { S += rs[i]; S2 += rs2[i]; }
        const float inv_n = 1.0f / (float)(T1_ * D_);
        float mu = S * inv_n;
        float var = S2 * inv_n - mu * mu;
        mu_s = mu; rstd_s = rsqrtf(var + 1e-5f);
    }
    __syncthreads();
    float mu = mu_s, rstd = rstd_s;
    f16* hb = hout + (size_t)b * (T1_ * D_);
    for (int i = tid; i < 4160; i += 1024) {
        float4 v = x4[i]; float4 wv = w4[i]; float4 bv = b4[i];
        f16x4 h;
        h[0] = (f16)((v.x - mu) * rstd * wv.x + bv.x);
        h[1] = (f16)((v.y - mu) * rstd * wv.y + bv.y);
        h[2] = (f16)((v.z - mu) * rstd * wv.z + bv.z);
        h[3] = (f16)((v.w - mu) * rstd * wv.w + bv.w);
        *(f16x4*)(hb + i * 4) = h;
    }
}

// ---------------- fast f16 GEMM: C = A[M][K] * Bt[N][K]^T, 2-phase dbuf -------
// EPI: 0=+bias, 1=+bias,relu, 2=+bias+residual, 3=+bias+residual dual f32/f16
template<int EPI, typename OutT>
__global__ __launch_bounds__(256) void gemm_f16(
        const f16* __restrict__ A, const f16* __restrict__ Bt,
        const float* __restrict__ bias, const float* __restrict__ Res,
        OutT* __restrict__ Cc, f16* __restrict__ C2, int M, int N, int K) {
    __shared__ __align__(16) f16 As[2][128 * 32];
    __shared__ __align__(16) f16 Bs[2][128 * 32];
    int nb = blockIdx.x, mb = blockIdx.y;
    int t = threadIdx.x;
    int lane = t & 63, wid = t >> 6;
    int wr = wid >> 1, wc = wid & 1;
    int lr = lane & 15, kq = lane >> 4;
    int row0 = mb * 128, col0 = nb * 128;

    f32x4 acc[4][4];
    #pragma unroll
    for (int mi = 0; mi < 4; ++mi)
        #pragma unroll
        for (int ni = 0; ni < 4; ++ni)
            #pragma unroll
            for (int r = 0; r < 4; ++r) acc[mi][ni][r] = 0.f;

    int sr = t >> 2;
    int k8 = (t & 3) * 8;
    const f16* Ab = A + (size_t)row0 * K + k8;
    const f16* Bb = Bt + (size_t)col0 * K + k8;

    // prologue: stage tile 0 into buf 0
    async16(Ab + (size_t)sr * K,        &As[0][t * 8]);
    async16(Ab + (size_t)(sr + 64) * K, &As[0][2048 + t * 8]);
    async16(Bb + (size_t)sr * K,        &Bs[0][t * 8]);
    async16(Bb + (size_t)(sr + 64) * K, &Bs[0][2048 + t * 8]);
    __syncthreads();

    int cur = 0;
    for (int k0 = 0; k0 < K; k0 += 32) {
        int nxt = cur ^ 1;
        if (k0 + 32 < K) {   // issue next-tile stage BEFORE compute (T3 min recipe)
            async16(Ab + (size_t)sr * K + k0 + 32,        &As[nxt][t * 8]);
            async16(Ab + (size_t)(sr + 64) * K + k0 + 32, &As[nxt][2048 + t * 8]);
            async16(Bb + (size_t)sr * K + k0 + 32,        &Bs[nxt][t * 8]);
            async16(Bb + (size_t)(sr + 64) * K + k0 + 32, &Bs[nxt][2048 + t * 8]);
        }
        f16x8 af[4], bf[4];
        #pragma unroll
        for (int mi = 0; mi < 4; ++mi)
            af[mi] = *(const f16x8*)&As[cur][(wr * 64 + mi * 16 + lr) * 32 + kq * 8];
        #pragma unroll
        for (int ni = 0; ni < 4; ++ni)
            bf[ni] = *(const f16x8*)&Bs[cur][(wc * 64 + ni * 16 + lr) * 32 + kq * 8];
        #pragma unroll
        for (int mi = 0; mi < 4; ++mi)
            #pragma unroll
            for (int ni = 0; ni < 4; ++ni)
                acc[mi][ni] = __builtin_amdgcn_mfma_f32_16x16x32_f16(af[mi], bf[ni], acc[mi][ni], 0, 0, 0);
        __syncthreads();   // drains vmcnt (stage done) + protects buffer swap
        cur = nxt;
    }

    #pragma unroll
    for (int mi = 0; mi < 4; ++mi) {
        #pragma unroll
        for (int ni = 0; ni < 4; ++ni) {
            int col = col0 + wc * 64 + ni * 16 + lr;
            #pragma unroll
            for (int r = 0; r < 4; ++r) {
                int row = row0 + wr * 64 + mi * 16 + kq * 4 + r;
                float v = acc[mi][ni][r] + bias[col];
                if (EPI == 1) v = fmaxf(v, 0.f);
                if (EPI == 2 || EPI == 3) v += Res[(size_t)row * N + col];
                Cc[(size_t)row * N + col] = (OutT)v;
                if (EPI == 3) C2[(size_t)row * N + col] = (f16)v;
            }
        }
    }
}

// ---------------- head1 GEMM: A f16 [256][16640], B f32 [16640][8192] ---------
// 2-phase dbuf; B reg-staged f32->f16 into swizzled [col][k] LDS so the inner
// loop is pure ds_read_b128 + MFMA (was: 32 conflicted scalar f32 reads + cvt)
__device__ __forceinline__ int bswz(int col, int k) {
    // f16 index; XOR k bits 3..4 with (col>>2)&3: breaks the 16-way write
    // conflict (all lanes had col%4 patterns mapping to 1 bank) down to 4-way.
    return col * 32 + (k ^ (((col >> 2) & 3) << 3));
}

__global__ __launch_bounds__(256) void gemm_head1(
        const f16* __restrict__ A, const float* __restrict__ Bw,
        float* __restrict__ Cp) {
    __shared__ __align__(16) f16 As[2][256 * 32];   // 16 KB each
    __shared__ __align__(16) f16 Bs[2][64 * 32];    // 4 KB each
    const int K = M_ROWS, N = HEAD_H_;
    int nb = blockIdx.x;
    int z = blockIdx.y;
    int t = threadIdx.x;
    int lane = t & 63, wid = t >> 6;
    int lr = lane & 15, kq = lane >> 4;
    int col0 = nb * 64;
    int kstart = z * (K / 4);
    int kend = kstart + K / 4;

    f32x4 acc[4][4];
    #pragma unroll
    for (int mi = 0; mi < 4; ++mi)
        #pragma unroll
        for (int ni = 0; ni < 4; ++ni)
            #pragma unroll
            for (int r = 0; r < 4; ++r) acc[mi][ni][r] = 0.f;

    int sr = t >> 2;
    int k8 = (t & 3) * 8;
    const f16* Ab = A + k8;
    int kp = (t >> 4) * 2;        // 0..30 (pair of k rows)
    int c0 = (t & 15) * 4;        // 0..60 (4 cols)
    const float* Bb = Bw + col0 + c0;

    f32x4 bv0, bv1;               // in-flight B registers (T14 split)

    auto stageA = [&](int buf, int k0) {
        #pragma unroll
        for (int r = 0; r < 4; ++r)
            async16(Ab + (size_t)(sr + r * 64) * K + k0, &As[buf][r * 2048 + t * 8]);
    };
    auto loadB = [&](int k0) {
        bv0 = *(const f32x4*)(Bb + (size_t)(k0 + kp) * N);
        bv1 = *(const f32x4*)(Bb + (size_t)(k0 + kp + 1) * N);
    };
    auto writeB = [&](int buf) {
        #pragma unroll
        for (int c = 0; c < 4; ++c) {
            f16x2 hv; hv[0] = (f16)bv0[c]; hv[1] = (f16)bv1[c];
            *(f16x2*)&Bs[buf][bswz(c0 + c, kp)] = hv;
        }
    };

    // prologue
    stageA(0, kstart);
    loadB(kstart);
    writeB(0);
    __syncthreads();

    int cur = 0;
    for (int k0 = kstart; k0 < kend; k0 += 32) {
        int nxt = cur ^ 1;
        bool pre = (k0 + 32 < kend);
        if (pre) {
            loadB(k0 + 32);         // issue early — latency hides under MFMA
            stageA(nxt, k0 + 32);
        }
        f16x8 af[4], bf[4];
        #pragma unroll
        for (int mi = 0; mi < 4; ++mi)
            af[mi] = *(const f16x8*)&As[cur][(wid * 64 + mi * 16 + lr) * 32 + kq * 8];
        #pragma unroll
        for (int ni = 0; ni < 4; ++ni)
            bf[ni] = *(const f16x8*)&Bs[cur][bswz(ni * 16 + lr, kq * 8)];
        #pragma unroll
        for (int mi = 0; mi < 4; ++mi)
            #pragma unroll
            for (int ni = 0; ni < 4; ++ni)
                acc[mi][ni] = __builtin_amdgcn_mfma_f32_16x16x32_f16(af[mi], bf[ni], acc[mi][ni], 0, 0, 0);
        if (pre) writeB(nxt);       // vmcnt wait lands here, after compute
        __syncthreads();
        cur = nxt;
    }

    float* Cout = Cp + (size_t)z * 256 * N;
    #pragma unroll
    for (int mi = 0; mi < 4; ++mi) {
        #pragma unroll
        for (int ni = 0; ni < 4; ++ni) {
            int col = col0 + ni * 16 + lr;
            #pragma unroll
            for (int r = 0; r < 4; ++r) {
                int row = wid * 64 + mi * 16 + kq * 4 + r;
                Cout[(size_t)row * N + col] = acc[mi][ni][r];
            }
        }
    }
}

// ---------------- MFMA attention, one block per (b,h) -------------------------
__global__ __launch_bounds__(256) void attn_kernel(
        const f16* __restrict__ qkv, const float* __restrict__ outres,
        float* __restrict__ r) {
    int b = blockIdx.x >> 3, h = blockIdx.x & 7;
    __shared__ __align__(16) f16 Qs[80 * 32];
    __shared__ __align__(16) f16 Ks[80 * 32];
    __shared__ __align__(16) f16 Vt[32 * 96];
    __shared__ float Sf[80 * 81];
    __shared__ __align__(16) f16 Pf[80 * 96];
    int tid = threadIdx.x;
    int lane = tid & 63, wid = tid >> 6;
    int lr = lane & 15, kq = lane >> 4;
    const float scale = 0.17677669529663687f;   // 1/sqrt(32)

    const f16* base = qkv + (size_t)b * T1_ * 768 + h * 96;
    for (int i = tid; i < T1_ * 12; i += 256) {
        int t = i / 12, c = i % 12;
        f16x8 vv = *(const f16x8*)(base + (size_t)t * 768 + c * 8);
        if (c < 4) {
            f16x8 q8;
            #pragma unroll
            for (int j = 0; j < 8; ++j) q8[j] = (f16)((float)vv[j] * scale);
            *(f16x8*)&Qs[t * 32 + c * 8] = q8;
        } else if (c < 8) {
            *(f16x8*)&Ks[t * 32 + (c - 4) * 8] = vv;
        } else {
            int d0 = (c - 8) * 8;
            #pragma unroll
            for (int j = 0; j < 8; ++j) Vt[(d0 + j) * 96 + t] = vv[j];
        }
    }
    for (int i = tid; i < 32 * 31; i += 256) {   // zero Vt pad cols 65..95
        int d = i / 31, kt = 65 + i % 31;
        Vt[d * 96 + kt] = (f16)0.f;
    }
    __syncthreads();

    // QK^T: 25 tiles of 16x16, K=32 (one MFMA step)
    for (int tile = wid; tile < 25; tile += 4) {
        int mi = tile / 5, ni = tile % 5;
        f16x8 a = *(const f16x8*)&Qs[(mi * 16 + lr) * 32 + kq * 8];
        f16x8 bb = *(const f16x8*)&Ks[(ni * 16 + lr) * 32 + kq * 8];
        f32x4 c = {0.f, 0.f, 0.f, 0.f};
        c = __builtin_amdgcn_mfma_f32_16x16x32_f16(a, bb, c, 0, 0, 0);
        #pragma unroll
        for (int rr2 = 0; rr2 < 4; ++rr2)
            Sf[(mi * 16 + kq * 4 + rr2) * 81 + ni * 16 + lr] = c[rr2];
    }
    __syncthreads();

    // softmax: 4 lanes per row
    for (int row = tid >> 2; row < T1_; row += 64) {
        int sub = tid & 3;
        float m = -1e30f;
        for (int kt = sub; kt < T1_; kt += 4) m = fmaxf(m, Sf[row * 81 + kt]);
        m = fmaxf(m, __shfl_xor(m, 1));
        m = fmaxf(m, __shfl_xor(m, 2));
        float sum = 0.f;
        for (int kt = sub; kt < T1_; kt += 4) {
            float e = __expf(Sf[row * 81 + kt] - m);
            Sf[row * 81 + kt] = e; sum += e;
        }
        sum += __shfl_xor(sum, 1);
        sum += __shfl_xor(sum, 2);
        float inv = 1.f / sum;
        for (int kt = sub; kt < T1_; kt += 4)
            Pf[row * 96 + kt] = (f16)(Sf[row * 81 + kt] * inv);
        for (int kt = T1_ + sub; kt < 96; kt += 4)
            Pf[row * 96 + kt] = (f16)0.f;
    }
    __syncthreads();

    // PV: 10 tiles (5 m x 2 n), K=96 (3 MFMA steps)
    for (int tile = wid; tile < 10; tile += 4) {
        int mi = tile >> 1, ni = tile & 1;
        f32x4 acc = {0.f, 0.f, 0.f, 0.f};
        #pragma unroll
        for (int ks = 0; ks < 3; ++ks) {
            f16x8 a = *(const f16x8*)&Pf[(mi * 16 + lr) * 96 + ks * 32 + kq * 8];
            f16x8 bv = *(const f16x8*)&Vt[(ni * 16 + lr) * 96 + ks * 32 + kq * 8];
            acc = __builtin_amdgcn_mfma_f32_16x16x32_f16(a, bv, acc, 0, 0, 0);
        }
        #pragma unroll
        for (int rr2 = 0; rr2 < 4; ++rr2) {
            int qt = mi * 16 + kq * 4 + rr2;
            if (qt < T1_) {
                size_t o = ((size_t)b * T1_ + qt) * D_ + h * HD_ + ni * 16 + lr;
                r[o] = acc[rr2] + outres[o];
            }
        }
    }
}

// ---------------- head2 fused: split-K combine + bias + silu + matvec ---------
__global__ __launch_bounds__(256) void head2_fused(
        const float* __restrict__ part, const float* __restrict__ h1b,
        const float* __restrict__ w, const float* __restrict__ h2b,
        float* __restrict__ out) {
    int b = blockIdx.x;
    const int NP = 256 * HEAD_H_;
    int tid = threadIdx.x;
    float acc[NCLS];
    #pragma unroll
    for (int n = 0; n < NCLS; ++n) acc[n] = 0.f;
    for (int kk = tid; kk < HEAD_H_; kk += 256) {
        size_t o = (size_t)b * HEAD_H_ + kk;
        float v = part[o] + part[o + NP] + part[o + 2 * (size_t)NP] + part[o + 3 * (size_t)NP]
                + h1b[kk];
        v = v / (1.f + __expf(-v));
        const float* wr = w + (size_t)kk * NCLS;
        #pragma unroll
        for (int n = 0; n < NCLS; ++n) acc[n] += v * wr[n];
    }
    #pragma unroll
    for (int n = 0; n < NCLS; ++n)
        #pragma unroll
        for (int o = 32; o > 0; o >>= 1) acc[n] += __shfl_down(acc[n], o);
    __shared__ float red[4][NCLS];
    int wid = tid >> 6;
    if ((tid & 63) == 0)
        for (int n = 0; n < NCLS; ++n) red[wid][n] = acc[n];
    __syncthreads();
    if (tid < NCLS) {
        int n = tid;
        out[(size_t)b * NCLS + n] = red[0][n] + red[1][n] + red[2][n] + red[3][n] + h2b[n];
    }
}

extern "C" void kernel_launch(void* const* d_in, const int* in_sizes, int n_in,
                              void* d_out, int out_size, void* d_ws, size_t ws_size,
                              hipStream_t stream) {
    (void)in_sizes; (void)n_in; (void)out_size; (void)ws_size;
    const float* x       = (const float*)d_in[0];
    const float* cls     = (const float*)d_in[1];
    const float* Wp      = (const float*)d_in[2];
    const float* bp      = (const float*)d_in[3];
    const float* qkv_w   = (const float*)d_in[4];
    const float* qkv_b   = (const float*)d_in[5];
    const float* ln_w    = (const float*)d_in[6];
    const float* ln_b    = (const float*)d_in[7];
    const float* mlp1_w  = (const float*)d_in[8];
    const float* mlp1_b  = (const float*)d_in[9];
    const float* mlp2_w  = (const float*)d_in[10];
    const float* mlp2_b  = (const float*)d_in[11];
    const float* head1_w = (const float*)d_in[12];
    const float* head1_b = (const float*)d_in[13];
    const float* head2_w = (const float*)d_in[14];
    const float* head2_b = (const float*)d_in[15];
    float* outp = (float*)d_out;

    char* ws = (char*)d_ws;
    size_t off = 0;
    auto alloc = [&](size_t bytes) -> void* {
        void* p = ws + off; off += (bytes + 255) & ~(size_t)255; return p;
    };
    float* s_out = (float*)alloc((size_t)M_ROWS * D_ * 4);
    float* s_r   = (float*)alloc((size_t)M_ROWS * D_ * 4);
    f16*   s_h   = (f16*)  alloc((size_t)M_ROWS * D_ * 2);
    void*  s_big = alloc((size_t)M_ROWS * MLP_H_ * 2);
    f16*   w_qkv_t  = (f16*)alloc((size_t)2 * 768 * 256 * 2);
    f16*   w_mlp1_t = (f16*)alloc((size_t)2 * 2048 * 256 * 2);
    f16*   w_mlp2_t = (f16*)alloc((size_t)2 * 256 * 2048 * 2);
    f16*   wpT      = (f16*)alloc((size_t)256 * 64 * 2);
    f16*   s_flat   = s_h;       // alias: dead after mlp1 of layer 2
    f16*   s_qkv = (f16*)s_big;
    f16*   s_m   = (f16*)s_big;
    float* s_part = (float*)s_big;

    dim3 blk(256);

    prep_weights<<<dim3(2496), blk, 0, stream>>>(
        qkv_w, mlp1_w, mlp2_w, Wp, w_qkv_t, w_mlp1_t, w_mlp2_t, wpT);
    patch_mfma<<<dim3(B_), blk, 0, stream>>>(x, cls, wpT, bp, s_out);

    for (int i = 0; i < 2; ++i) {
        const float* lw = ln_w + (size_t)i * T1_ * D_;
        const float* lb = ln_b + (size_t)i * T1_ * D_;
        ln_kernel<<<dim3(B_), dim3(1024), 0, stream>>>(s_out, lw, lb, s_h);
        gemm_f16<0, f16><<<dim3(768 / 128, M_ROWS / 128), blk, 0, stream>>>(
            s_h, w_qkv_t + (size_t)i * 768 * 256, qkv_b + (size_t)i * 768,
            nullptr, s_qkv, nullptr, M_ROWS, 768, 256);
        attn_kernel<<<dim3(B_ * H_), blk, 0, stream>>>(s_qkv, s_out, s_r);
        ln_kernel<<<dim3(B_), dim3(1024), 0, stream>>>(s_r, lw, lb, s_h);
        gemm_f16<1, f16><<<dim3(MLP_H_ / 128, M_ROWS / 128), blk, 0, stream>>>(
            s_h, w_mlp1_t + (size_t)i * 2048 * 256, mlp1_b + (size_t)i * MLP_H_,
            nullptr, s_m, nullptr, M_ROWS, MLP_H_, 256);
        if (i == 0) {
            gemm_f16<2, float><<<dim3(D_ / 128, M_ROWS / 128), blk, 0, stream>>>(
                s_m, w_mlp2_t + (size_t)i * 256 * 2048, mlp2_b + (size_t)i * D_,
                s_r, s_out, nullptr, M_ROWS, D_, MLP_H_);
        } else {
            gemm_f16<3, float><<<dim3(D_ / 128, M_ROWS / 128), blk, 0, stream>>>(
                s_m, w_mlp2_t + (size_t)i * 256 * 2048, mlp2_b + (size_t)i * D_,
                s_r, s_out, s_flat, M_ROWS, D_, MLP_H_);
        }
    }

    gemm_head1<<<dim3(HEAD_H_ / 64, 4), blk, 0, stream>>>(s_flat, head1_w, s_part);
    head2_fused<<<dim3(B_), blk, 0, stream>>>(s_part, head1_b, head2_w, head2_b, outp);
}